// Round 21
// baseline (171.327 us; speedup 1.0000x reference)
//
#include <hip/hip_runtime.h>
#include <hip/hip_bf16.h>

#define EPS 1e-8f

using short8 = __attribute__((ext_vector_type(8))) short;
using f32x16 = __attribute__((ext_vector_type(16))) float;
typedef unsigned short u16;

#define BARRIER() do { __builtin_amdgcn_s_barrier(); \
                       asm volatile("" ::: "memory"); } while (0)
#define LGKM0() asm volatile("s_waitcnt lgkmcnt(0)" ::: "memory")

__device__ __forceinline__ u16 f2bf(float f) {
    union { float f; unsigned u; } v; v.f = f;
    unsigned u = v.u;
    return (u16)((u + 0x7FFFu + ((u >> 16) & 1u)) >> 16);
}

// ---------------- kernel 1: style[b][i] = dot(w[b], affine_w[i]) + affine_b[i] + 1
__global__ void style_kernel(const float* __restrict__ w,        // [8][512]
                             const float* __restrict__ affine_w, // [256][512]
                             const float* __restrict__ affine_b, // [256]
                             float* __restrict__ style) {        // [8][256]
    int b = blockIdx.x;
    int i = threadIdx.x;
    __shared__ float wb[512];
    for (int z = threadIdx.x; z < 512; z += 256) wb[z] = w[b * 512 + z];
    __syncthreads();
    const float* aw = affine_w + i * 512;
    float acc = 0.f;
#pragma unroll 4
    for (int z = 0; z < 512; z += 4) {
        float4 a4 = *reinterpret_cast<const float4*>(aw + z);
        acc += a4.x * wb[z] + a4.y * wb[z + 1] + a4.z * wb[z + 2] + a4.w * wb[z + 3];
    }
    style[b * 256 + i] = acc + affine_b[i] + 1.0f;
}

// ---------------- kernel 2: modulate + demodulate, pack bf16 weights
// wgt layout: bf16 [b][t(9)][g(32)][o(256)][j(8)], ic = g*8 + j
__global__ void modw_kernel(const float* __restrict__ weight, // [256][256][3][3]
                            const float* __restrict__ style,  // [8][256]
                            u16* __restrict__ wgt) {
    int b = blockIdx.x >> 8;
    int o = blockIdx.x & 255;
    int ic = threadIdx.x; // 256 threads
    float s = style[b * 256 + ic];
    const float* wp = weight + (size_t)(o * 256 + ic) * 9;
    float m[9];
    float ss = 0.f;
#pragma unroll
    for (int t = 0; t < 9; ++t) { m[t] = wp[t] * s; ss += m[t] * m[t]; }
#pragma unroll
    for (int off = 32; off > 0; off >>= 1) ss += __shfl_down(ss, off);
    __shared__ float part[4];
    int lane = threadIdx.x & 63, wid = threadIdx.x >> 6;
    if (lane == 0) part[wid] = ss;
    __syncthreads();
    float denom = rsqrtf(part[0] + part[1] + part[2] + part[3] + EPS);
    int g = ic >> 3, j = ic & 7;
#pragma unroll
    for (int t = 0; t < 9; ++t) {
        size_t idx = ((((size_t)(b * 9 + t) * 32 + g) * 256 + o) << 3) + j;
        wgt[idx] = f2bf(m[t] * denom);
    }
}

// ---------------- kernel 3: fused implicit-GEMM conv (R20 + staging after MFMA)
// block = (b, ot, ht): 128 o x (2 rows x 128 w), 256 threads (4 waves), 2 blocks/CU.
// A: global->VGPR per wave (L2-resident), 1-tap prefetch afC/afN.
// X staging per (row,g) unit: 4 float4 issues; cvt-pack; permlane32_swap halves;
//    two ds_write_b128. CHANGE vs R20: the staging block (writeX(t-1), issueX(t))
//    moves AFTER the MFMA cluster — the tap's bx8 ds_reads and MFMA start
//    immediately (staging VALU/ds_writes land in the post-MFMA shadow where the
//    co-wave's MFMA burst keeps the matrix pipe busy and VALU/LDS slots free).
//    Single xg slot preserved (writeX before issueX). FIFO: afN precedes issueX,
//    so A-waits never drain X; issueX->writeX cover = ~1 tap > HBM latency.
// Chunk boundary: lgkmcnt(0) + barrier. OOB rows never written (zeros persist).
__global__ __launch_bounds__(256, 2) void conv_kernel(
    const float* __restrict__ x,  // [8][256][128][128] fp32
    const u16* __restrict__ wgt,  // [8][9][32][256][8] bf16
    float* __restrict__ out) {    // [8][256][128][128]

    __shared__ __align__(16) u16 Xs[2][4][4][130][8]; // 66560 B [buf][row][g][w130][j8]

    int bid = blockIdx.x;
    int swz = (bid & 7) * 128 + (bid >> 3); // grid 1024 = 8*128, bijective
    int ht = swz & 63, ot = (swz >> 6) & 1, b = swz >> 7;
    int h0 = ht * 2;

    int tid = threadIdx.x, lane = tid & 63, wid = tid >> 6;
    int wm = wid >> 1, wr = wid & 1; // wave -> (o half 64, row)
    int l31 = lane & 31, lh = lane >> 5;
    int lw = lane & 31, hi = lane >> 5;     // staging lane split
    int jbase = hi * 4;                      // lanes>=32 handle j-planes 4..7
    int koff = hi * 2;                       // w sub-index base after swap

    int hr = h0 + wid - 1;
    bool hValid = ((unsigned)hr < 128u);
    int hc = hValid ? hr : 0;

    // per-lane bases
    const u16* aBase = wgt + ((size_t)(b * 9) * 32 * 256 +
                              (size_t)(lh * 256 + ot * 128 + wm * 64 + l31)) * 8;
    const float* xSt = x + (((size_t)(b * 256 + jbase)) * 128 + hc) * 128 + 4 * lw;

    auto loadA = [&](short8 dst[2][2], int c, int t) {
#pragma unroll
        for (int kk = 0; kk < 2; ++kk)
#pragma unroll
            for (int mi = 0; mi < 2; ++mi)
                dst[kk][mi] = *reinterpret_cast<const short8*>(
                    aBase + (size_t)(((t * 32) + c * 4 + kk * 2) * 256 + mi * 32) * 8);
    };
    // unit g of chunk c1, row = wid: 4 float4 issues (j-planes jbase..jbase+3)
    auto issueX = [&](float* dst, int c1, int g) {
        const float* sp = xSt + (size_t)(c1 * 32 + g * 8) * 16384;
#pragma unroll
        for (int i = 0; i < 4; ++i)
            *reinterpret_cast<float4*>(&dst[i * 4]) =
                *reinterpret_cast<const float4*>(sp + (size_t)i * 16384);
    };
    auto writeX = [&](const float* src, int g, int bx) {
        // pack: X[k][d] = bf16x2 of (F_{2d}[k], F_{2d+1}[k]); F_i[k] = src[i*4+k]
        unsigned X[4][2];
#pragma unroll
        for (int k = 0; k < 4; ++k)
#pragma unroll
            for (int d = 0; d < 2; ++d) {
                __hip_bfloat16 b0 = __float2bfloat16(src[(2 * d) * 4 + k]);
                __hip_bfloat16 b1 = __float2bfloat16(src[(2 * d + 1) * 4 + k]);
                X[k][d] = (unsigned)reinterpret_cast<u16&>(b0) |
                          ((unsigned)reinterpret_cast<u16&>(b1) << 16);
            }
        // half-exchange: after swap(A=X[ka][d], B=X[ka+2][d]):
        //   A' = lo: LO_ka | hi: LO_{ka+2};  B' = lo: HI_ka | hi: HI_{ka+2}
        unsigned a00 = X[0][0], c00 = X[2][0];
        unsigned a01 = X[0][1], c01 = X[2][1];
        unsigned a10 = X[1][0], c10 = X[3][0];
        unsigned a11 = X[1][1], c11 = X[3][1];
        asm volatile("v_permlane32_swap_b32 %0, %1" : "+v"(a00), "+v"(c00));
        asm volatile("v_permlane32_swap_b32 %0, %1" : "+v"(a01), "+v"(c01));
        asm volatile("v_permlane32_swap_b32 %0, %1" : "+v"(a10), "+v"(c10));
        asm volatile("v_permlane32_swap_b32 %0, %1" : "+v"(a11), "+v"(c11));
        union { unsigned d[4]; short8 v; } oA, oB;
        oA.d[0] = a00; oA.d[1] = a01; oA.d[2] = c00; oA.d[3] = c01; // octet w=4lw+koff
        oB.d[0] = a10; oB.d[1] = a11; oB.d[2] = c10; oB.d[3] = c11; // octet w=4lw+koff+1
        int slotA = 1 + 4 * lw + koff;
        *reinterpret_cast<short8*>(&Xs[bx][wid][g][slotA][0])     = oA.v;
        *reinterpret_cast<short8*>(&Xs[bx][wid][g][slotA + 1][0]) = oB.v;
    };

    // zero both X buffers (borders + OOB rows stay zero forever)
    {
        short8 z = {0, 0, 0, 0, 0, 0, 0, 0};
        short8* p0 = reinterpret_cast<short8*>(&Xs[0][0][0][0][0]);
        for (int i = tid; i < 4160; i += 256) p0[i] = z;
    }
    __syncthreads();

    short8 afC[2][2], afN[2][2];
    // prologue: stage chunk 0 into buf 0, unit by unit (bounded registers)
    if (hValid) {
        float xg0[16];
#pragma unroll
        for (int g = 0; g < 4; ++g) { issueX(xg0, 0, g); writeX(xg0, g, 0); }
    }
    loadA(afC, 0, 0);
    LGKM0();
    BARRIER();

    f32x16 acc[2][4] = {};
    float xg[16]; // single staging slot: write(t-1) then issue(t) reuses it

    for (int c = 0; c < 8; ++c) {
        int buf = c & 1;
        bool stage = (c < 7) && hValid;
#pragma unroll
        for (int t = 0; t < 9; ++t) {
            bool lastTap = (c == 7 && t == 8);
            if (!lastTap)
                loadA(afN, t < 8 ? c : c + 1, t < 8 ? t + 1 : 0);

            int kh = t / 3, kw = t - kh * 3;
            short8 bx8[2][4];
#pragma unroll
            for (int kk = 0; kk < 2; ++kk)
#pragma unroll
                for (int ni = 0; ni < 4; ++ni)
                    bx8[kk][ni] = *reinterpret_cast<const short8*>(
                        &Xs[buf][wr + kh][kk * 2 + lh][ni * 32 + l31 + kw][0]);
#pragma unroll
            for (int mi = 0; mi < 2; ++mi)
#pragma unroll
                for (int ni = 0; ni < 4; ++ni)
#pragma unroll
                    for (int kk = 0; kk < 2; ++kk)
                        acc[mi][ni] = __builtin_amdgcn_mfma_f32_32x32x16_bf16(
                            afC[kk][mi], bx8[kk][ni], acc[mi][ni], 0, 0, 0);

            // staging AFTER the MFMA cluster (post-MFMA shadow)
            if (stage) {
                if (t >= 1 && t < 5) writeX(xg, t - 1, buf ^ 1); // unit t-1
                if (t < 4)           issueX(xg, c + 1, t);       // unit t
            }

            if (!lastTap) {
#pragma unroll
                for (int k2 = 0; k2 < 2; ++k2)
#pragma unroll
                    for (int mi = 0; mi < 2; ++mi)
                        afC[k2][mi] = afN[k2][mi];
            }
        }
        if (c < 7) { LGKM0(); BARRIER(); } // ds_writes of chunk c+1 visible block-wide
    }

    // epilogue: C/D 32x32 layout col=lane&31 (w), row=(reg&3)+8*(reg>>2)+4*(lane>>5) (o)
    int h = h0 + wr;
#pragma unroll
    for (int mi = 0; mi < 2; ++mi) {
        int ob = ot * 128 + wm * 64 + mi * 32 + 4 * lh;
#pragma unroll
        for (int ni = 0; ni < 4; ++ni) {
            int w_ = ni * 32 + l31;
#pragma unroll
            for (int reg = 0; reg < 16; ++reg) {
                int o = ob + (reg & 3) + 8 * (reg >> 2);
                out[(((size_t)(b * 256 + o) * 128 + h) * 128) + w_] = acc[mi][ni][reg];
            }
        }
    }
}

extern "C" void kernel_launch(void* const* d_in, const int* in_sizes, int n_in,
                              void* d_out, int out_size, void* d_ws, size_t ws_size,
                              hipStream_t stream) {
    const float* x        = (const float*)d_in[0];
    const float* w        = (const float*)d_in[1];
    const float* weight   = (const float*)d_in[2];
    const float* affine_w = (const float*)d_in[3];
    const float* affine_b = (const float*)d_in[4];
    float* out = (float*)d_out;

    float* style = (float*)d_ws;                                   // 8 KB
    u16* wgt = (u16*)((char*)d_ws + 8192);                         // 9.44 MB

    style_kernel<<<8, 256, 0, stream>>>(w, affine_w, affine_b, style);
    modw_kernel<<<2048, 256, 0, stream>>>(weight, style, wgt);
    conv_kernel<<<1024, 256, 0, stream>>>(x, wgt, out);
}

// Round 22
// 170.654 us; speedup vs baseline: 1.0039x; 1.0039x over previous
//
#include <hip/hip_runtime.h>
#include <hip/hip_bf16.h>

#define EPS 1e-8f

using short8 = __attribute__((ext_vector_type(8))) short;
using f32x16 = __attribute__((ext_vector_type(16))) float;
typedef unsigned short u16;

#define BARRIER() do { __builtin_amdgcn_s_barrier(); \
                       asm volatile("" ::: "memory"); } while (0)
#define LGKM0() asm volatile("s_waitcnt lgkmcnt(0)" ::: "memory")

__device__ __forceinline__ u16 f2bf(float f) {
    union { float f; unsigned u; } v; v.f = f;
    unsigned u = v.u;
    return (u16)((u + 0x7FFFu + ((u >> 16) & 1u)) >> 16);
}

// ---------------- kernel 1: style[b][i] = dot(w[b], affine_w[i]) + affine_b[i] + 1
__global__ void style_kernel(const float* __restrict__ w,        // [8][512]
                             const float* __restrict__ affine_w, // [256][512]
                             const float* __restrict__ affine_b, // [256]
                             float* __restrict__ style) {        // [8][256]
    int b = blockIdx.x;
    int i = threadIdx.x;
    __shared__ float wb[512];
    for (int z = threadIdx.x; z < 512; z += 256) wb[z] = w[b * 512 + z];
    __syncthreads();
    const float* aw = affine_w + i * 512;
    float acc = 0.f;
#pragma unroll 4
    for (int z = 0; z < 512; z += 4) {
        float4 a4 = *reinterpret_cast<const float4*>(aw + z);
        acc += a4.x * wb[z] + a4.y * wb[z + 1] + a4.z * wb[z + 2] + a4.w * wb[z + 3];
    }
    style[b * 256 + i] = acc + affine_b[i] + 1.0f;
}

// ---------------- kernel 2: modulate + demodulate, pack bf16 weights
// wgt layout: bf16 [b][t(9)][g(32)][o(256)][j(8)], ic = g*8 + j
__global__ void modw_kernel(const float* __restrict__ weight, // [256][256][3][3]
                            const float* __restrict__ style,  // [8][256]
                            u16* __restrict__ wgt) {
    int b = blockIdx.x >> 8;
    int o = blockIdx.x & 255;
    int ic = threadIdx.x; // 256 threads
    float s = style[b * 256 + ic];
    const float* wp = weight + (size_t)(o * 256 + ic) * 9;
    float m[9];
    float ss = 0.f;
#pragma unroll
    for (int t = 0; t < 9; ++t) { m[t] = wp[t] * s; ss += m[t] * m[t]; }
#pragma unroll
    for (int off = 32; off > 0; off >>= 1) ss += __shfl_down(ss, off);
    __shared__ float part[4];
    int lane = threadIdx.x & 63, wid = threadIdx.x >> 6;
    if (lane == 0) part[wid] = ss;
    __syncthreads();
    float denom = rsqrtf(part[0] + part[1] + part[2] + part[3] + EPS);
    int g = ic >> 3, j = ic & 7;
#pragma unroll
    for (int t = 0; t < 9; ++t) {
        size_t idx = ((((size_t)(b * 9 + t) * 32 + g) * 256 + o) << 3) + j;
        wgt[idx] = f2bf(m[t] * denom);
    }
}

// ---------------- kernel 3: fused implicit-GEMM conv (R20 structure)
// block = (b, ot, ht): 128 o x (2 rows x 128 w), 256 threads (4 waves), 2 blocks/CU.
// A: global->VGPR per wave (L2-resident), 1-tap prefetch afC/afN.
// X staging per (row,g) unit: 4 float4 issues; cvt-pack; permlane32_swap halves
//    (asm NON-volatile: data deps preserve correctness, scheduler may interleave
//    the cvt/swap stream into ds_read/MFMA slots instead of a serial burst);
//    two ds_write_b128 (unit g issued tap t=g, written tap t+1; single 16-reg slot,
//    staging placed BEFORE the MFMA cluster — R21's after-MFMA placement regressed).
// No setprio (R20 A/B: removal was +5us — T5 starves the co-wave at 2 waves/SIMD).
// Chunk boundary: lgkmcnt(0) + barrier. OOB rows never written (zeros persist).
__global__ __launch_bounds__(256, 2) void conv_kernel(
    const float* __restrict__ x,  // [8][256][128][128] fp32
    const u16* __restrict__ wgt,  // [8][9][32][256][8] bf16
    float* __restrict__ out) {    // [8][256][128][128]

    __shared__ __align__(16) u16 Xs[2][4][4][130][8]; // 66560 B [buf][row][g][w130][j8]

    int bid = blockIdx.x;
    int swz = (bid & 7) * 128 + (bid >> 3); // grid 1024 = 8*128, bijective
    int ht = swz & 63, ot = (swz >> 6) & 1, b = swz >> 7;
    int h0 = ht * 2;

    int tid = threadIdx.x, lane = tid & 63, wid = tid >> 6;
    int wm = wid >> 1, wr = wid & 1; // wave -> (o half 64, row)
    int l31 = lane & 31, lh = lane >> 5;
    int lw = lane & 31, hi = lane >> 5;     // staging lane split
    int jbase = hi * 4;                      // lanes>=32 handle j-planes 4..7
    int koff = hi * 2;                       // w sub-index base after swap

    int hr = h0 + wid - 1;
    bool hValid = ((unsigned)hr < 128u);
    int hc = hValid ? hr : 0;

    // per-lane bases
    const u16* aBase = wgt + ((size_t)(b * 9) * 32 * 256 +
                              (size_t)(lh * 256 + ot * 128 + wm * 64 + l31)) * 8;
    const float* xSt = x + (((size_t)(b * 256 + jbase)) * 128 + hc) * 128 + 4 * lw;

    auto loadA = [&](short8 dst[2][2], int c, int t) {
#pragma unroll
        for (int kk = 0; kk < 2; ++kk)
#pragma unroll
            for (int mi = 0; mi < 2; ++mi)
                dst[kk][mi] = *reinterpret_cast<const short8*>(
                    aBase + (size_t)(((t * 32) + c * 4 + kk * 2) * 256 + mi * 32) * 8);
    };
    // unit g of chunk c1, row = wid: 4 float4 issues (j-planes jbase..jbase+3)
    auto issueX = [&](float* dst, int c1, int g) {
        const float* sp = xSt + (size_t)(c1 * 32 + g * 8) * 16384;
#pragma unroll
        for (int i = 0; i < 4; ++i)
            *reinterpret_cast<float4*>(&dst[i * 4]) =
                *reinterpret_cast<const float4*>(sp + (size_t)i * 16384);
    };
    auto writeX = [&](const float* src, int g, int bx) {
        // pack: X[k][d] = bf16x2 of (F_{2d}[k], F_{2d+1}[k]); F_i[k] = src[i*4+k]
        unsigned X[4][2];
#pragma unroll
        for (int k = 0; k < 4; ++k)
#pragma unroll
            for (int d = 0; d < 2; ++d) {
                __hip_bfloat16 b0 = __float2bfloat16(src[(2 * d) * 4 + k]);
                __hip_bfloat16 b1 = __float2bfloat16(src[(2 * d + 1) * 4 + k]);
                X[k][d] = (unsigned)reinterpret_cast<u16&>(b0) |
                          ((unsigned)reinterpret_cast<u16&>(b1) << 16);
            }
        // half-exchange: after swap(A=X[ka][d], B=X[ka+2][d]):
        //   A' = lo: LO_ka | hi: LO_{ka+2};  B' = lo: HI_ka | hi: HI_{ka+2}
        unsigned a00 = X[0][0], c00 = X[2][0];
        unsigned a01 = X[0][1], c01 = X[2][1];
        unsigned a10 = X[1][0], c10 = X[3][0];
        unsigned a11 = X[1][1], c11 = X[3][1];
        asm("v_permlane32_swap_b32 %0, %1" : "+v"(a00), "+v"(c00));
        asm("v_permlane32_swap_b32 %0, %1" : "+v"(a01), "+v"(c01));
        asm("v_permlane32_swap_b32 %0, %1" : "+v"(a10), "+v"(c10));
        asm("v_permlane32_swap_b32 %0, %1" : "+v"(a11), "+v"(c11));
        union { unsigned d[4]; short8 v; } oA, oB;
        oA.d[0] = a00; oA.d[1] = a01; oA.d[2] = c00; oA.d[3] = c01; // octet w=4lw+koff
        oB.d[0] = a10; oB.d[1] = a11; oB.d[2] = c10; oB.d[3] = c11; // octet w=4lw+koff+1
        int slotA = 1 + 4 * lw + koff;
        *reinterpret_cast<short8*>(&Xs[bx][wid][g][slotA][0])     = oA.v;
        *reinterpret_cast<short8*>(&Xs[bx][wid][g][slotA + 1][0]) = oB.v;
    };

    // zero both X buffers (borders + OOB rows stay zero forever)
    {
        short8 z = {0, 0, 0, 0, 0, 0, 0, 0};
        short8* p0 = reinterpret_cast<short8*>(&Xs[0][0][0][0][0]);
        for (int i = tid; i < 4160; i += 256) p0[i] = z;
    }
    __syncthreads();

    short8 afC[2][2], afN[2][2];
    // prologue: stage chunk 0 into buf 0, unit by unit (bounded registers)
    if (hValid) {
        float xg0[16];
#pragma unroll
        for (int g = 0; g < 4; ++g) { issueX(xg0, 0, g); writeX(xg0, g, 0); }
    }
    loadA(afC, 0, 0);
    LGKM0();
    BARRIER();

    f32x16 acc[2][4] = {};
    float xg[16]; // single staging slot: write(t-1) then issue(t) reuses it

    for (int c = 0; c < 8; ++c) {
        int buf = c & 1;
        bool stage = (c < 7) && hValid;
#pragma unroll
        for (int t = 0; t < 9; ++t) {
            bool lastTap = (c == 7 && t == 8);
            if (!lastTap)
                loadA(afN, t < 8 ? c : c + 1, t < 8 ? t + 1 : 0);
            if (stage) {
                if (t >= 1 && t < 5) writeX(xg, t - 1, buf ^ 1); // unit t-1
                if (t < 4)           issueX(xg, c + 1, t);       // unit t
            }

            int kh = t / 3, kw = t - kh * 3;
            short8 bx8[2][4];
#pragma unroll
            for (int kk = 0; kk < 2; ++kk)
#pragma unroll
                for (int ni = 0; ni < 4; ++ni)
                    bx8[kk][ni] = *reinterpret_cast<const short8*>(
                        &Xs[buf][wr + kh][kk * 2 + lh][ni * 32 + l31 + kw][0]);
#pragma unroll
            for (int mi = 0; mi < 2; ++mi)
#pragma unroll
                for (int ni = 0; ni < 4; ++ni)
#pragma unroll
                    for (int kk = 0; kk < 2; ++kk)
                        acc[mi][ni] = __builtin_amdgcn_mfma_f32_32x32x16_bf16(
                            afC[kk][mi], bx8[kk][ni], acc[mi][ni], 0, 0, 0);

            if (!lastTap) {
#pragma unroll
                for (int k2 = 0; k2 < 2; ++k2)
#pragma unroll
                    for (int mi = 0; mi < 2; ++mi)
                        afC[k2][mi] = afN[k2][mi];
            }
        }
        if (c < 7) { LGKM0(); BARRIER(); } // ds_writes of chunk c+1 visible block-wide
    }

    // epilogue: C/D 32x32 layout col=lane&31 (w), row=(reg&3)+8*(reg>>2)+4*(lane>>5) (o)
    int h = h0 + wr;
#pragma unroll
    for (int mi = 0; mi < 2; ++mi) {
        int ob = ot * 128 + wm * 64 + mi * 32 + 4 * lh;
#pragma unroll
        for (int ni = 0; ni < 4; ++ni) {
            int w_ = ni * 32 + l31;
#pragma unroll
            for (int reg = 0; reg < 16; ++reg) {
                int o = ob + (reg & 3) + 8 * (reg >> 2);
                out[(((size_t)(b * 256 + o) * 128 + h) * 128) + w_] = acc[mi][ni][reg];
            }
        }
    }
}

extern "C" void kernel_launch(void* const* d_in, const int* in_sizes, int n_in,
                              void* d_out, int out_size, void* d_ws, size_t ws_size,
                              hipStream_t stream) {
    const float* x        = (const float*)d_in[0];
    const float* w        = (const float*)d_in[1];
    const float* weight   = (const float*)d_in[2];
    const float* affine_w = (const float*)d_in[3];
    const float* affine_b = (const float*)d_in[4];
    float* out = (float*)d_out;

    float* style = (float*)d_ws;                                   // 8 KB
    u16* wgt = (u16*)((char*)d_ws + 8192);                         // 9.44 MB

    style_kernel<<<8, 256, 0, stream>>>(w, affine_w, affine_b, style);
    modw_kernel<<<2048, 256, 0, stream>>>(weight, style, wgt);
    conv_kernel<<<1024, 256, 0, stream>>>(x, wgt, out);
}

// Round 24
// 167.229 us; speedup vs baseline: 1.0245x; 1.0205x over previous
//
#include <hip/hip_runtime.h>
#include <hip/hip_bf16.h>

#define EPS 1e-8f

using short8 = __attribute__((ext_vector_type(8))) short;
using f32x16 = __attribute__((ext_vector_type(16))) float;
typedef unsigned short u16;

#define BARRIER() do { __builtin_amdgcn_s_barrier(); \
                       asm volatile("" ::: "memory"); } while (0)
#define LGKM0() asm volatile("s_waitcnt lgkmcnt(0)" ::: "memory")

__device__ __forceinline__ u16 f2bf(float f) {
    union { float f; unsigned u; } v; v.f = f;
    unsigned u = v.u;
    return (u16)((u + 0x7FFFu + ((u >> 16) & 1u)) >> 16);
}

// per-8-block rotation swizzle (write AND read sides).
// Bijective on [0,129]; identity on block 0 and the tail {128,129}.
// Writes (s = 1+4l+koff) land on all 8 bank-quad residues across 8 lanes.
__device__ __forceinline__ int swz(int s) {
    return (s & ~7) | ((s + (s >> 3)) & 7);
}

// ---------------- kernel 1: style[b][i] = dot(w[b], affine_w[i]) + affine_b[i] + 1
__global__ void style_kernel(const float* __restrict__ w,        // [8][512]
                             const float* __restrict__ affine_w, // [256][512]
                             const float* __restrict__ affine_b, // [256]
                             float* __restrict__ style) {        // [8][256]
    int b = blockIdx.x;
    int i = threadIdx.x;
    __shared__ float wb[512];
    for (int z = threadIdx.x; z < 512; z += 256) wb[z] = w[b * 512 + z];
    __syncthreads();
    const float* aw = affine_w + i * 512;
    float acc = 0.f;
#pragma unroll 4
    for (int z = 0; z < 512; z += 4) {
        float4 a4 = *reinterpret_cast<const float4*>(aw + z);
        acc += a4.x * wb[z] + a4.y * wb[z + 1] + a4.z * wb[z + 2] + a4.w * wb[z + 3];
    }
    style[b * 256 + i] = acc + affine_b[i] + 1.0f;
}

// ---------------- kernel 2: modulate + demodulate, pack bf16 weights
// wgt layout: bf16 [b][t(9)][g(32)][o(256)][j(8)], ic = g*8 + j
__global__ void modw_kernel(const float* __restrict__ weight, // [256][256][3][3]
                            const float* __restrict__ style,  // [8][256]
                            u16* __restrict__ wgt) {
    int b = blockIdx.x >> 8;
    int o = blockIdx.x & 255;
    int ic = threadIdx.x; // 256 threads
    float s = style[b * 256 + ic];
    const float* wp = weight + (size_t)(o * 256 + ic) * 9;
    float m[9];
    float ss = 0.f;
#pragma unroll
    for (int t = 0; t < 9; ++t) { m[t] = wp[t] * s; ss += m[t] * m[t]; }
#pragma unroll
    for (int off = 32; off > 0; off >>= 1) ss += __shfl_down(ss, off);
    __shared__ float part[4];
    int lane = threadIdx.x & 63, wid = threadIdx.x >> 6;
    if (lane == 0) part[wid] = ss;
    __syncthreads();
    float denom = rsqrtf(part[0] + part[1] + part[2] + part[3] + EPS);
    int g = ic >> 3, j = ic & 7;
#pragma unroll
    for (int t = 0; t < 9; ++t) {
        size_t idx = ((((size_t)(b * 9 + t) * 32 + g) * 256 + o) << 3) + j;
        wgt[idx] = f2bf(m[t] * denom);
    }
}

// ---------------- kernel 3: fused implicit-GEMM conv (R20 + rotation bank swizzle)
// block = (b, ot, ht): 128 o x (2 rows x 128 w), 256 threads (4 waves), 2 blocks/CU.
// A: global->VGPR per wave (L2-resident), 1-tap prefetch afC/afN. No setprio (R20 A/B).
// X staging per (row,g) unit: 4 float4 issues; cvt-pack; permlane32_swap halves;
//    two ds_write_b128 at ROTATION-SWIZZLED slots (conflict-free: 8 consecutive
//    lanes cover all 8 bank-quad residues). Reads apply the same swizzle; 32
//    consecutive logical slots stay per-8-block bijective -> read floor kept.
// R23 bug fixed: aBase parenthesization (b-term must also be *8; R23 indexed
// 1/8-scale for b>0 -> absmax 7.56. Swizzle itself re-verified bijective).
// Chunk boundary: lgkmcnt(0) + barrier. OOB rows never written (zeros persist).
__global__ __launch_bounds__(256, 2) void conv_kernel(
    const float* __restrict__ x,  // [8][256][128][128] fp32
    const u16* __restrict__ wgt,  // [8][9][32][256][8] bf16
    float* __restrict__ out) {    // [8][256][128][128]

    __shared__ __align__(16) u16 Xs[2][4][4][130][8]; // 66560 B [buf][row][g][w130][j8]

    int bid = blockIdx.x;
    int swzb = (bid & 7) * 128 + (bid >> 3); // grid 1024 = 8*128, bijective
    int ht = swzb & 63, ot = (swzb >> 6) & 1, b = swzb >> 7;
    int h0 = ht * 2;

    int tid = threadIdx.x, lane = tid & 63, wid = tid >> 6;
    int wm = wid >> 1, wr = wid & 1; // wave -> (o half 64, row)
    int l31 = lane & 31, lh = lane >> 5;
    int lw = lane & 31, hi = lane >> 5;     // staging lane split
    int jbase = hi * 4;                      // lanes>=32 handle j-planes 4..7
    int koff = hi * 2;                       // w sub-index base after swap

    int hr = h0 + wid - 1;
    bool hValid = ((unsigned)hr < 128u);
    int hc = hValid ? hr : 0;

    // per-lane bases
    const u16* aBase = wgt + ((size_t)(b * 9) * 32 * 256 +
                              (size_t)(lh * 256 + ot * 128 + wm * 64 + l31)) * 8;
    const float* xSt = x + (((size_t)(b * 256 + jbase)) * 128 + hc) * 128 + 4 * lw;

    auto loadA = [&](short8 dst[2][2], int c, int t) {
#pragma unroll
        for (int kk = 0; kk < 2; ++kk)
#pragma unroll
            for (int mi = 0; mi < 2; ++mi)
                dst[kk][mi] = *reinterpret_cast<const short8*>(
                    aBase + (size_t)(((t * 32) + c * 4 + kk * 2) * 256 + mi * 32) * 8);
    };
    // unit g of chunk c1, row = wid: 4 float4 issues (j-planes jbase..jbase+3)
    auto issueX = [&](float* dst, int c1, int g) {
        const float* sp = xSt + (size_t)(c1 * 32 + g * 8) * 16384;
#pragma unroll
        for (int i = 0; i < 4; ++i)
            *reinterpret_cast<float4*>(&dst[i * 4]) =
                *reinterpret_cast<const float4*>(sp + (size_t)i * 16384);
    };
    auto writeX = [&](const float* src, int g, int bx) {
        // pack: X[k][d] = bf16x2 of (F_{2d}[k], F_{2d+1}[k]); F_i[k] = src[i*4+k]
        unsigned X[4][2];
#pragma unroll
        for (int k = 0; k < 4; ++k)
#pragma unroll
            for (int d = 0; d < 2; ++d) {
                __hip_bfloat16 b0 = __float2bfloat16(src[(2 * d) * 4 + k]);
                __hip_bfloat16 b1 = __float2bfloat16(src[(2 * d + 1) * 4 + k]);
                X[k][d] = (unsigned)reinterpret_cast<u16&>(b0) |
                          ((unsigned)reinterpret_cast<u16&>(b1) << 16);
            }
        // half-exchange: after swap(A=X[ka][d], B=X[ka+2][d]):
        //   A' = lo: LO_ka | hi: LO_{ka+2};  B' = lo: HI_ka | hi: HI_{ka+2}
        unsigned a00 = X[0][0], c00 = X[2][0];
        unsigned a01 = X[0][1], c01 = X[2][1];
        unsigned a10 = X[1][0], c10 = X[3][0];
        unsigned a11 = X[1][1], c11 = X[3][1];
        asm("v_permlane32_swap_b32 %0, %1" : "+v"(a00), "+v"(c00));
        asm("v_permlane32_swap_b32 %0, %1" : "+v"(a01), "+v"(c01));
        asm("v_permlane32_swap_b32 %0, %1" : "+v"(a10), "+v"(c10));
        asm("v_permlane32_swap_b32 %0, %1" : "+v"(a11), "+v"(c11));
        union { unsigned d[4]; short8 v; } oA, oB;
        oA.d[0] = a00; oA.d[1] = a01; oA.d[2] = c00; oA.d[3] = c01; // octet w=4lw+koff
        oB.d[0] = a10; oB.d[1] = a11; oB.d[2] = c10; oB.d[3] = c11; // octet w=4lw+koff+1
        int slotA = 1 + 4 * lw + koff;
        *reinterpret_cast<short8*>(&Xs[bx][wid][g][swz(slotA)][0])     = oA.v;
        *reinterpret_cast<short8*>(&Xs[bx][wid][g][swz(slotA + 1)][0]) = oB.v;
    };

    // zero both X buffers (borders + OOB rows stay zero forever)
    {
        short8 z = {0, 0, 0, 0, 0, 0, 0, 0};
        short8* p0 = reinterpret_cast<short8*>(&Xs[0][0][0][0][0]);
        for (int i = tid; i < 4160; i += 256) p0[i] = z;
    }
    __syncthreads();

    short8 afC[2][2], afN[2][2];
    // prologue: stage chunk 0 into buf 0, unit by unit (bounded registers)
    if (hValid) {
        float xg0[16];
#pragma unroll
        for (int g = 0; g < 4; ++g) { issueX(xg0, 0, g); writeX(xg0, g, 0); }
    }
    loadA(afC, 0, 0);
    LGKM0();
    BARRIER();

    f32x16 acc[2][4] = {};
    float xg[16]; // single staging slot: write(t-1) then issue(t) reuses it

    for (int c = 0; c < 8; ++c) {
        int buf = c & 1;
        bool stage = (c < 7) && hValid;
#pragma unroll
        for (int t = 0; t < 9; ++t) {
            bool lastTap = (c == 7 && t == 8);
            if (!lastTap)
                loadA(afN, t < 8 ? c : c + 1, t < 8 ? t + 1 : 0);
            if (stage) {
                if (t >= 1 && t < 5) writeX(xg, t - 1, buf ^ 1); // unit t-1
                if (t < 4)           issueX(xg, c + 1, t);       // unit t
            }

            int kh = t / 3, kw = t - kh * 3;
            int pr[4];
#pragma unroll
            for (int ni = 0; ni < 4; ++ni) pr[ni] = swz(ni * 32 + l31 + kw);
            short8 bx8[2][4];
#pragma unroll
            for (int kk = 0; kk < 2; ++kk)
#pragma unroll
                for (int ni = 0; ni < 4; ++ni)
                    bx8[kk][ni] = *reinterpret_cast<const short8*>(
                        &Xs[buf][wr + kh][kk * 2 + lh][pr[ni]][0]);
#pragma unroll
            for (int mi = 0; mi < 2; ++mi)
#pragma unroll
                for (int ni = 0; ni < 4; ++ni)
#pragma unroll
                    for (int kk = 0; kk < 2; ++kk)
                        acc[mi][ni] = __builtin_amdgcn_mfma_f32_32x32x16_bf16(
                            afC[kk][mi], bx8[kk][ni], acc[mi][ni], 0, 0, 0);

            if (!lastTap) {
#pragma unroll
                for (int k2 = 0; k2 < 2; ++k2)
#pragma unroll
                    for (int mi = 0; mi < 2; ++mi)
                        afC[k2][mi] = afN[k2][mi];
            }
        }
        if (c < 7) { LGKM0(); BARRIER(); } // ds_writes of chunk c+1 visible block-wide
    }

    // epilogue: C/D 32x32 layout col=lane&31 (w), row=(reg&3)+8*(reg>>2)+4*(lane>>5) (o)
    int h = h0 + wr;
#pragma unroll
    for (int mi = 0; mi < 2; ++mi) {
        int ob = ot * 128 + wm * 64 + mi * 32 + 4 * lh;
#pragma unroll
        for (int ni = 0; ni < 4; ++ni) {
            int w_ = ni * 32 + l31;
#pragma unroll
            for (int reg = 0; reg < 16; ++reg) {
                int o = ob + (reg & 3) + 8 * (reg >> 2);
                out[(((size_t)(b * 256 + o) * 128 + h) * 128) + w_] = acc[mi][ni][reg];
            }
        }
    }
}

extern "C" void kernel_launch(void* const* d_in, const int* in_sizes, int n_in,
                              void* d_out, int out_size, void* d_ws, size_t ws_size,
                              hipStream_t stream) {
    const float* x        = (const float*)d_in[0];
    const float* w        = (const float*)d_in[1];
    const float* weight   = (const float*)d_in[2];
    const float* affine_w = (const float*)d_in[3];
    const float* affine_b = (const float*)d_in[4];
    float* out = (float*)d_out;

    float* style = (float*)d_ws;                                   // 8 KB
    u16* wgt = (u16*)((char*)d_ws + 8192);                         // 9.44 MB

    style_kernel<<<8, 256, 0, stream>>>(w, affine_w, affine_b, style);
    modw_kernel<<<2048, 256, 0, stream>>>(weight, style, wgt);
    conv_kernel<<<1024, 256, 0, stream>>>(x, wgt, out);
}